// Round 3
// baseline (1683.005 us; speedup 1.0000x reference)
//
#include <hip/hip_runtime.h>
#include <math.h>

// dims
#define Bv 2
#define Cv 64
#define Hv 512
#define Wv 512
#define Kv 1024
#define KMAXv 256
#define HIDv 128
#define HWv (Hv * Wv) // 262144

// output flat offsets (f32 elements)
#define OFF_HEAVY 0
#define OFF_DETAIL 33554432
#define OFF_ALPHA 67108864
#define OFF_PROB 67633152
#define OFF_GATES 67635200
#define OFF_EC 67637248
#define OFF_BL 67637249

// ws layout (bytes): selflag int[2048] @0 ; cost float[2] @8192
#define WS_SEL_OFF 0
#define WS_COST_OFF 8192

// ---------------- selection + probabilities/gates + cost partials ----------------
__global__ __launch_bounds__(1024) void sel_kernel(const float* __restrict__ u,
                                                   float* __restrict__ out,
                                                   int* __restrict__ selflag,
                                                   float* __restrict__ costp) {
    int b = blockIdx.x;
    int t = threadIdx.x;
    __shared__ float us[Kv];
    __shared__ float red[16];

    float ui = u[b * Kv + t];
    us[t] = ui;
    __syncthreads();

    float p = 1.0f / (1.0f + __expf(-ui));
    float hard = (ui >= 0.0f) ? 1.0f : 0.0f;
    out[OFF_PROB + b * Kv + t] = p;
    out[OFF_GATES + b * Kv + t] = (hard + p) - p; // STE forward, ref op order

    float cost = p + (1.0f - p) * 0.1f;
    #pragma unroll
    for (int o = 32; o > 0; o >>= 1) cost += __shfl_down(cost, o, 64);
    int wave = t >> 6, lane = t & 63;
    if (lane == 0) red[wave] = cost;
    __syncthreads();
    if (t == 0) {
        float s = 0.f;
        #pragma unroll
        for (int i = 0; i < 16; i++) s += red[i];
        costp[b] = s;
    }

    // rank among masked values (stable top-k tie-break by lower index)
    int selected = 0;
    if (ui >= 0.0f) {
        int r = 0;
        for (int j = 0; j < Kv; j += 4) {
            float4 uj = *(const float4*)&us[j];
            r += (uj.x > ui) || (uj.x == ui && (j + 0) < t);
            r += (uj.y > ui) || (uj.y == ui && (j + 1) < t);
            r += (uj.z > ui) || (uj.z == ui && (j + 2) < t);
            r += (uj.w > ui) || (uj.w == ui && (j + 3) < t);
        }
        selected = (r < KMAXv) ? 1 : 0;
    }
    selflag[b * Kv + t] = selected;
}

// ---------------- fused kernel: half-pair blocks (8 rows x 32 cols, 2 adjacent tiles) ----------------
// 2048 blocks x 256 threads. Full 128B-line writes everywhere.
__global__ __launch_bounds__(256, 4) void fused_kernel(const float* __restrict__ x,
                                                       const float* __restrict__ W1,
                                                       const float* __restrict__ b1,
                                                       const float* __restrict__ W2,
                                                       const float* __restrict__ b2,
                                                       const float* __restrict__ Wa,
                                                       const float* __restrict__ ba,
                                                       float* __restrict__ out,
                                                       const int* __restrict__ selflag,
                                                       const float* __restrict__ costp) {
    int blk = blockIdx.x;
    int t = threadIdx.x;

    if (blk == 0 && t == 0) {
        float ec = costp[0] + costp[1];
        out[OFF_EC] = ec;
        out[OFF_BL] = (ec > 1024.0f) ? (ec - 1024.0f) : 0.0f;
    }

    int b = blk >> 10;
    int rem = blk & 1023;
    int pairid = rem >> 1;   // 0..511
    int half = rem & 1;      // top/bottom 8 rows
    int gh = pairid >> 4;    // 0..31
    int gp = pairid & 15;    // 0..15
    int h0 = gh * 16 + half * 8;
    int w0 = gp * 32;

    int tA = b * Kv + gh * 32 + gp * 2;
    int selA = selflag[tA];
    int selB = selflag[tA + 1];

    if ((selA | selB) == 0) {
        // pure copy path: float4, rows are 128B lines
        int pl = t >> 6;          // 0..3 channel sub-plane
        int r = (t >> 3) & 7;     // row 0..7
        int q = t & 7;            // float4 within 32-wide row
        int base = ((b * Cv + pl) * Hv + h0 + r) * Wv + w0 + q * 4;
        float4 z = make_float4(0.f, 0.f, 0.f, 0.f);
        #pragma unroll 4
        for (int it = 0; it < 16; it++) {
            int idx = base + it * 4 * HWv;
            float4 v = *(const float4*)&x[idx];
            *(float4*)&out[OFF_HEAVY + idx] = v;
            *(float4*)&out[OFF_DETAIL + idx] = z;
        }
        if (t < 64) {
            int r2 = t >> 3, q2 = t & 7;
            int aidx = (b * Hv + h0 + r2) * Wv + w0 + q2 * 4;
            *(float4*)&out[OFF_ALPHA + aidx] = z;
        }
        return;
    }

    // ---- MLP path: one pixel per thread, per-lane sel mask, no divergence ----
    int r = t >> 5;          // 0..7
    int cc = t & 31;         // 0..31 (cc<16 -> tile A, else tile B)
    float msk = (cc < 16) ? (float)selA : (float)selB;
    int pbase = (b * Cv * Hv + h0 + r) * Wv + w0 + cc;

    // alpha sweep
    float aacc = ba[0];
    for (int c0 = 0; c0 < Cv; c0 += 8) {
        float xv[8];
        #pragma unroll
        for (int k = 0; k < 8; k++) xv[k] = x[pbase + (c0 + k) * HWv];
        #pragma unroll
        for (int k = 0; k < 8; k++) aacc += xv[k] * Wa[c0 + k];
    }
    float alpha = 1.0f / (1.0f + __expf(-aacc));
    float am = msk * alpha;
    out[OFF_ALPHA + (b * Hv + h0 + r) * Wv + w0 + cc] = am;

    // detail accumulators init to b2
    float D[Cv];
    #pragma unroll
    for (int c4 = 0; c4 < 16; c4++) {
        float4 bb = *(const float4*)&b2[c4 * 4];
        D[4 * c4 + 0] = bb.x; D[4 * c4 + 1] = bb.y;
        D[4 * c4 + 2] = bb.z; D[4 * c4 + 3] = bb.w;
    }

    // hid-chunked two-layer MLP (4 chunks of 32)
    for (int d0 = 0; d0 < HIDv; d0 += 32) {
        float Hc[32];
        #pragma unroll
        for (int j4 = 0; j4 < 8; j4++) {
            float4 bb = *(const float4*)&b1[d0 + 4 * j4];
            Hc[4 * j4 + 0] = bb.x; Hc[4 * j4 + 1] = bb.y;
            Hc[4 * j4 + 2] = bb.z; Hc[4 * j4 + 3] = bb.w;
        }
        // layer 1: Hc[j] += x_c * W1[c][d0+j], x batched 8-deep
        for (int c0 = 0; c0 < Cv; c0 += 8) {
            float xv[8];
            #pragma unroll
            for (int k = 0; k < 8; k++) xv[k] = x[pbase + (c0 + k) * HWv];
            #pragma unroll
            for (int k = 0; k < 8; k++) {
                float xc = xv[k];
                const float4* w1p = (const float4*)(W1 + (c0 + k) * HIDv + d0);
                #pragma unroll
                for (int j4 = 0; j4 < 8; j4++) {
                    float4 w = w1p[j4];
                    Hc[4 * j4 + 0] += xc * w.x;
                    Hc[4 * j4 + 1] += xc * w.y;
                    Hc[4 * j4 + 2] += xc * w.z;
                    Hc[4 * j4 + 3] += xc * w.w;
                }
            }
        }
        // gelu (tanh approx, matches jax.nn.gelu)
        #pragma unroll
        for (int j = 0; j < 32; j++) {
            float zv = Hc[j];
            float zz = 0.7978845608028654f * (zv + 0.044715f * zv * zv * zv);
            float e = __expf(2.0f * zz);
            float th = 1.0f - 2.0f / (e + 1.0f);
            Hc[j] = 0.5f * zv * (1.0f + th);
        }
        // layer 2: D[c] += Hc[j] * W2[d0+j][c] (native row layout)
        #pragma unroll 4
        for (int j = 0; j < 32; j++) {
            float hj = Hc[j];
            const float4* w2p = (const float4*)(W2 + (d0 + j) * Cv);
            #pragma unroll
            for (int c4 = 0; c4 < 16; c4++) {
                float4 w = w2p[c4];
                D[4 * c4 + 0] += hj * w.x;
                D[4 * c4 + 1] += hj * w.y;
                D[4 * c4 + 2] += hj * w.z;
                D[4 * c4 + 3] += hj * w.w;
            }
        }
    }

    // epilogue: re-read x (L2-hot), blend with mask, full-line stores
    for (int c0 = 0; c0 < Cv; c0 += 8) {
        float xv[8];
        #pragma unroll
        for (int k = 0; k < 8; k++) xv[k] = x[pbase + (c0 + k) * HWv];
        #pragma unroll
        for (int k = 0; k < 8; k++) {
            int idx = pbase + (c0 + k) * HWv;
            float det = D[c0 + k];
            out[OFF_DETAIL + idx] = msk * det;
            out[OFF_HEAVY + idx] = xv[k] + am * det;
        }
    }
}

extern "C" void kernel_launch(void* const* d_in, const int* in_sizes, int n_in,
                              void* d_out, int out_size, void* d_ws, size_t ws_size,
                              hipStream_t stream) {
    const float* x  = (const float*)d_in[0];
    const float* u  = (const float*)d_in[1];
    const float* W1 = (const float*)d_in[2];
    const float* b1 = (const float*)d_in[3];
    const float* W2 = (const float*)d_in[4];
    const float* b2 = (const float*)d_in[5];
    const float* Wa = (const float*)d_in[6];
    const float* ba = (const float*)d_in[7];
    float* out = (float*)d_out;

    char* ws = (char*)d_ws;
    int*   selflag = (int*)(ws + WS_SEL_OFF);
    float* costp   = (float*)(ws + WS_COST_OFF);

    sel_kernel<<<Bv, 1024, 0, stream>>>(u, out, selflag, costp);
    fused_kernel<<<Bv * Kv, 256, 0, stream>>>(x, W1, b1, W2, b2, Wa, ba, out, selflag, costp);
}